// Round 1
// baseline (132.048 us; speedup 1.0000x reference)
//
#include <hip/hip_runtime.h>
#include <hip/hip_fp16.h>
#include <cmath>

#define DF 128            // feature dim
#define WPITCHH 136       // LDS W row pitch in halves (128 + 8 pad, 272 B)

typedef _Float16 f16x8 __attribute__((ext_vector_type(8)));
typedef _Float16 f16x4 __attribute__((ext_vector_type(4)));
typedef float    f32x4 __attribute__((ext_vector_type(4)));

// ---------------------------------------------------------------------------
// Kernel A: fused {edge-meta build + CSR rowptr} + {support GEMM via MFMA}.
// Meta work is grid-strided across the GEMM grid and issued FIRST so its
// loads/stores overlap the block's W-staging + X-load latency. W is converted
// fp32->fp16 on the fly while staging into LDS (removes the build->gemm
// dependency that previously forced a third kernel).
// GEMM: one 64-lane wave per 16-row m-strip, 4 waves/block, operand-swapped
// mfma(W,X) so the epilogue is 8 f16x4 stores per lane.
// ---------------------------------------------------------------------------
__global__ __launch_bounds__(256)
void gemm_meta_kernel(const float* __restrict__ X, const float* __restrict__ W,
                      const float* __restrict__ bias, __half* __restrict__ S,
                      const int* __restrict__ arow, const int* __restrict__ acol,
                      const float* __restrict__ aval,
                      int* __restrict__ rowptr, int2* __restrict__ pk,
                      int N, int E, int nthreads)
{
    __shared__ _Float16 Wl[DF * WPITCHH];          // 34 KB

    const int t   = threadIdx.x;
    const int tid = blockIdx.x * 256 + t;

    // ---- meta: packed edge {byte_offset, val_bits} + CSR rowptr ----
    for (int e = tid; e < E; e += nthreads) {
        pk[e] = make_int2(acol[e] << 8, __float_as_int(aval[e]));
        int r     = arow[e];
        int rprev = (e == 0) ? -1 : arow[e - 1];
        for (int n = rprev + 1; n <= r; ++n) rowptr[n] = e;
        if (e == E - 1) {
            for (int n = r + 1; n <= N; ++n) rowptr[n] = E;
        }
    }

    // ---- stage W into LDS, converting fp32 -> fp16 in flight ----
    #pragma unroll
    for (int l = 0; l < 8; ++l) {
        int flat = l * 256 + t;                    // 0..2047
        int r    = flat >> 4;                      // 0..127
        int c8   = (flat & 15) * 8;                // 0..120
        const float* wp = W + (size_t)r * DF + c8;
        float4 wa = *(const float4*)wp;
        float4 wb = *(const float4*)(wp + 4);
        f16x8 v;
        v[0] = (_Float16)wa.x; v[1] = (_Float16)wa.y;
        v[2] = (_Float16)wa.z; v[3] = (_Float16)wa.w;
        v[4] = (_Float16)wb.x; v[5] = (_Float16)wb.y;
        v[6] = (_Float16)wb.z; v[7] = (_Float16)wb.w;
        *(f16x8*)(Wl + r * WPITCHH + c8) = v;
    }
    __syncthreads();

    const int lane = t & 63;
    const int l15  = lane & 15;
    const int q    = lane >> 4;                    // 0..3
    const int m0   = (blockIdx.x * 4 + (t >> 6)) * 16;
    if (m0 >= N) return;

    f32x4 acc[8];
    #pragma unroll
    for (int nt = 0; nt < 8; ++nt) acc[nt] = (f32x4){0.f, 0.f, 0.f, 0.f};

    const int xrow = min(m0 + l15, N - 1);         // clamp (dup read) for tail
    #pragma unroll
    for (int kc = 0; kc < DF; kc += 32) {
        const float* xp = X + (size_t)xrow * DF + kc + q * 8;
        float4 xa = *(const float4*)xp;
        float4 xb = *(const float4*)(xp + 4);
        f16x8 A;
        A[0] = (_Float16)xa.x; A[1] = (_Float16)xa.y;
        A[2] = (_Float16)xa.z; A[3] = (_Float16)xa.w;
        A[4] = (_Float16)xb.x; A[5] = (_Float16)xb.y;
        A[6] = (_Float16)xb.z; A[7] = (_Float16)xb.w;
        #pragma unroll
        for (int nt = 0; nt < 8; ++nt) {
            f16x8 B = *(const f16x8*)(Wl + (nt * 16 + l15) * WPITCHH + kc + q * 8);
            // swapped: first operand = W rows (o), second = X rows (node)
            acc[nt] = __builtin_amdgcn_mfma_f32_16x16x32_f16(B, A, acc[nt], 0, 0, 0);
        }
    }

    const int mrow = m0 + l15;
    if (mrow < N) {
        _Float16* rowp = (_Float16*)S + (size_t)mrow * DF;
        #pragma unroll
        for (int nt = 0; nt < 8; ++nt) {
            float4 bv = *(const float4*)(bias + nt * 16 + q * 4);
            f16x4 hv;
            hv[0] = (_Float16)(acc[nt][0] + bv.x);
            hv[1] = (_Float16)(acc[nt][1] + bv.y);
            hv[2] = (_Float16)(acc[nt][2] + bv.z);
            hv[3] = (_Float16)(acc[nt][3] + bv.w);
            *(f16x4*)(rowp + nt * 16 + q * 4) = hv;
        }
    }
}

// ---------------------------------------------------------------------------
// Kernel B: out[n][:] = tanh( sum_e val[e]*S_fp16[col[e]][:] ), ONE WAVE PER
// NODE. lane = (f, es) with f = lane>>2 (feature 16B chunk 0..15), es = lane&3
// (edge slot 0..3): one 64-lane gather instruction covers 4 edges x 256 B.
// 8 edges (2 gathers) in flight per iteration; trip count is per-node uniform
// (no inter-node divergence). Padded slots read row 0 with val=0. Epilogue:
// 2-step shfl_xor reduce over the 4 es-lanes of each cluster, then each lane
// writes float2 at out[n][lane*2] -> one fully contiguous 512 B wave store.
// ---------------------------------------------------------------------------
__global__ __launch_bounds__(256)
void agg_tanh_kernel(const __half* __restrict__ S, const int* __restrict__ rowptr,
                     const int2* __restrict__ pk, float* __restrict__ out, int Nn)
{
    const int n = (blockIdx.x * 256 + threadIdx.x) >> 6;    // node = wave
    if (n >= Nn) return;
    const int lane = threadIdx.x & 63;
    const int es   = lane & 3;                              // edge slot
    const int f    = lane >> 2;                             // feature chunk
    const int fb   = f * 16;                                // byte offset in row

    const int start = rowptr[n];
    const int end   = rowptr[n + 1];
    const char* Sb  = (const char*)S;

    float acc[8];
    #pragma unroll
    for (int i = 0; i < 8; ++i) acc[i] = 0.f;

    for (int e = start; e < end; e += 8) {
        const int ea = e + es;
        int2 pa = (ea < end) ? pk[ea] : make_int2(0, 0);
        f16x8 ha = *(const f16x8*)(Sb + (size_t)(unsigned)pa.x + fb);
        const float va = __int_as_float(pa.y);
        if (e + 4 < end) {                                  // wave-uniform
            const int eb = ea + 4;
            int2 pb = (eb < end) ? pk[eb] : make_int2(0, 0);
            f16x8 hb = *(const f16x8*)(Sb + (size_t)(unsigned)pb.x + fb);
            const float vb = __int_as_float(pb.y);
            #pragma unroll
            for (int i = 0; i < 8; ++i)
                acc[i] += (float)ha[i] * va + (float)hb[i] * vb;
        } else {
            #pragma unroll
            for (int i = 0; i < 8; ++i)
                acc[i] += (float)ha[i] * va;
        }
    }

    // reduce across the 4 es-lanes of each cluster (masks 1 and 2)
    #pragma unroll
    for (int i = 0; i < 8; ++i) {
        acc[i] += __shfl_xor(acc[i], 1, 64);
        acc[i] += __shfl_xor(acc[i], 2, 64);
    }

    // lane owns features lane*2, lane*2+1  (= f*8 + es*2 + {0,1})
    float a0, a1;
    if      (es == 0) { a0 = acc[0]; a1 = acc[1]; }
    else if (es == 1) { a0 = acc[2]; a1 = acc[3]; }
    else if (es == 2) { a0 = acc[4]; a1 = acc[5]; }
    else              { a0 = acc[6]; a1 = acc[7]; }

    float2 o;
    o.x = tanhf(a0);
    o.y = tanhf(a1);
    *(float2*)(out + (size_t)n * DF + lane * 2) = o;
}

// ---------------------------------------------------------------------------
extern "C" void kernel_launch(void* const* d_in, const int* in_sizes, int n_in,
                              void* d_out, int out_size, void* d_ws, size_t ws_size,
                              hipStream_t stream)
{
    const float* X    = (const float*)d_in[0];   // [N, 128]
    const float* W    = (const float*)d_in[1];   // [128, 128]
    const float* bias = (const float*)d_in[2];   // [128]
    const int*   arow = (const int*)  d_in[3];   // [E] sorted
    const int*   acol = (const int*)  d_in[4];   // [E]
    const float* aval = (const float*)d_in[5];   // [E]
    float* out = (float*)d_out;

    const int N = in_sizes[0] / DF;
    const int E = in_sizes[3];

    // ws layout: S [N*128 fp16] | rowptr [N+2] | pk [E int2]
    __half* S      = (__half*)d_ws;
    int*    rowptr = (int*)((char*)d_ws + (size_t)N * DF * sizeof(__half));
    int2*   pk     = (int2*)(rowptr + (N + 2));

    const int gemmBlocks = (N + 63) / 64;
    gemm_meta_kernel<<<gemmBlocks, 256, 0, stream>>>(X, W, bias, S,
                                                     arow, acol, aval,
                                                     rowptr, pk, N, E,
                                                     gemmBlocks * 256);

    agg_tanh_kernel<<<(N * 64 + 255) / 256, 256, 0, stream>>>(S, rowptr, pk, out, N);
}

// Round 2
// 124.476 us; speedup vs baseline: 1.0608x; 1.0608x over previous
//
#include <hip/hip_runtime.h>
#include <hip/hip_fp16.h>
#include <cmath>

#define DF 128            // feature dim
#define WPITCHH 136       // LDS W row pitch in halves (128 + 8 pad, 272 B)

typedef _Float16 f16x8 __attribute__((ext_vector_type(8)));
typedef _Float16 f16x4 __attribute__((ext_vector_type(4)));
typedef float    f32x4 __attribute__((ext_vector_type(4)));

// ---------------------------------------------------------------------------
// Kernel A: fused {edge-meta build + CSR rowptr} + {support GEMM via MFMA}.
// Meta work is grid-strided across the GEMM grid and issued FIRST so its
// loads/stores overlap the block's W-staging + X-load latency. W is converted
// fp32->fp16 on the fly while staging into LDS (removes the build->gemm
// dependency that previously forced a third kernel).
// GEMM: one 64-lane wave per 16-row m-strip, 4 waves/block, operand-swapped
// mfma(W,X) so the epilogue is 8 f16x4 stores per lane.
// ---------------------------------------------------------------------------
__global__ __launch_bounds__(256)
void gemm_meta_kernel(const float* __restrict__ X, const float* __restrict__ W,
                      const float* __restrict__ bias, __half* __restrict__ S,
                      const int* __restrict__ arow, const int* __restrict__ acol,
                      const float* __restrict__ aval,
                      int* __restrict__ rowptr, int2* __restrict__ pk,
                      int N, int E, int nthreads)
{
    __shared__ _Float16 Wl[DF * WPITCHH];          // 34 KB

    const int t   = threadIdx.x;
    const int tid = blockIdx.x * 256 + t;

    // ---- meta: packed edge {byte_offset, val_bits} + CSR rowptr ----
    for (int e = tid; e < E; e += nthreads) {
        pk[e] = make_int2(acol[e] << 8, __float_as_int(aval[e]));
        int r     = arow[e];
        int rprev = (e == 0) ? -1 : arow[e - 1];
        for (int n = rprev + 1; n <= r; ++n) rowptr[n] = e;
        if (e == E - 1) {
            for (int n = r + 1; n <= N; ++n) rowptr[n] = E;
        }
    }

    // ---- stage W into LDS, converting fp32 -> fp16 in flight ----
    #pragma unroll
    for (int l = 0; l < 8; ++l) {
        int flat = l * 256 + t;                    // 0..2047
        int r    = flat >> 4;                      // 0..127
        int c8   = (flat & 15) * 8;                // 0..120
        const float* wp = W + (size_t)r * DF + c8;
        float4 wa = *(const float4*)wp;
        float4 wb = *(const float4*)(wp + 4);
        f16x8 v;
        v[0] = (_Float16)wa.x; v[1] = (_Float16)wa.y;
        v[2] = (_Float16)wa.z; v[3] = (_Float16)wa.w;
        v[4] = (_Float16)wb.x; v[5] = (_Float16)wb.y;
        v[6] = (_Float16)wb.z; v[7] = (_Float16)wb.w;
        *(f16x8*)(Wl + r * WPITCHH + c8) = v;
    }
    __syncthreads();

    const int lane = t & 63;
    const int l15  = lane & 15;
    const int q    = lane >> 4;                    // 0..3
    const int m0   = (blockIdx.x * 4 + (t >> 6)) * 16;
    if (m0 >= N) return;

    f32x4 acc[8];
    #pragma unroll
    for (int nt = 0; nt < 8; ++nt) acc[nt] = (f32x4){0.f, 0.f, 0.f, 0.f};

    const int xrow = min(m0 + l15, N - 1);         // clamp (dup read) for tail
    #pragma unroll
    for (int kc = 0; kc < DF; kc += 32) {
        const float* xp = X + (size_t)xrow * DF + kc + q * 8;
        float4 xa = *(const float4*)xp;
        float4 xb = *(const float4*)(xp + 4);
        f16x8 A;
        A[0] = (_Float16)xa.x; A[1] = (_Float16)xa.y;
        A[2] = (_Float16)xa.z; A[3] = (_Float16)xa.w;
        A[4] = (_Float16)xb.x; A[5] = (_Float16)xb.y;
        A[6] = (_Float16)xb.z; A[7] = (_Float16)xb.w;
        #pragma unroll
        for (int nt = 0; nt < 8; ++nt) {
            f16x8 B = *(const f16x8*)(Wl + (nt * 16 + l15) * WPITCHH + kc + q * 8);
            // swapped: first operand = W rows (o), second = X rows (node)
            acc[nt] = __builtin_amdgcn_mfma_f32_16x16x32_f16(B, A, acc[nt], 0, 0, 0);
        }
    }

    const int mrow = m0 + l15;
    if (mrow < N) {
        _Float16* rowp = (_Float16*)S + (size_t)mrow * DF;
        #pragma unroll
        for (int nt = 0; nt < 8; ++nt) {
            float4 bv = *(const float4*)(bias + nt * 16 + q * 4);
            f16x4 hv;
            hv[0] = (_Float16)(acc[nt][0] + bv.x);
            hv[1] = (_Float16)(acc[nt][1] + bv.y);
            hv[2] = (_Float16)(acc[nt][2] + bv.z);
            hv[3] = (_Float16)(acc[nt][3] + bv.w);
            *(f16x4*)(rowp + nt * 16 + q * 4) = hv;
        }
    }
}

// ---------------------------------------------------------------------------
// Kernel B (EXACT round-0 proven version): out[n][:] = tanh( sum_e
// val[e]*S_fp16[col[e]][:] ) per CSR row. ONE 16-LANE GROUP PER NODE
// (4 nodes/wave, 16 nodes/block): lane f owns features 8f..8f+7 (16 B chunk),
// 16 lanes cover the whole 256 B row, no cross-lane reduction. 4-edge unroll:
// 4 pk loads + 4 gathers in flight per group. Padded slots read row 0 with
// val=0. Reverted from wave-per-node (round 1, -8.6us regression).
// ---------------------------------------------------------------------------
__global__ __launch_bounds__(256)
void agg_tanh_kernel(const __half* __restrict__ S, const int* __restrict__ rowptr,
                     const int2* __restrict__ pk, float* __restrict__ out, int Nn)
{
    const int n  = (blockIdx.x * 256 + threadIdx.x) >> 4;   // node = global group
    if (n >= Nn) return;
    const int f  = threadIdx.x & 15;                        // feature chunk
    const int fb = f * 16;                                  // byte offset in row

    const int start = rowptr[n];
    const int end   = rowptr[n + 1];
    const char* Sb  = (const char*)S;

    float acc[8];
    #pragma unroll
    for (int i = 0; i < 8; ++i) acc[i] = 0.f;

    for (int e = start; e < end; e += 4) {
        int2 p0 = pk[e];
        int2 p1 = (e + 1 < end) ? pk[e + 1] : make_int2(0, 0);
        int2 p2 = (e + 2 < end) ? pk[e + 2] : make_int2(0, 0);
        int2 p3 = (e + 3 < end) ? pk[e + 3] : make_int2(0, 0);
        f16x8 h0 = *(const f16x8*)(Sb + (size_t)(unsigned)p0.x + fb);
        f16x8 h1 = *(const f16x8*)(Sb + (size_t)(unsigned)p1.x + fb);
        f16x8 h2 = *(const f16x8*)(Sb + (size_t)(unsigned)p2.x + fb);
        f16x8 h3 = *(const f16x8*)(Sb + (size_t)(unsigned)p3.x + fb);
        const float v0 = __int_as_float(p0.y);
        const float v1 = __int_as_float(p1.y);
        const float v2 = __int_as_float(p2.y);
        const float v3 = __int_as_float(p3.y);
        #pragma unroll
        for (int i = 0; i < 8; ++i) {
            acc[i] += (float)h0[i] * v0 + (float)h1[i] * v1
                    + (float)h2[i] * v2 + (float)h3[i] * v3;
        }
    }

    float4 o0, o1;
    o0.x = tanhf(acc[0]); o0.y = tanhf(acc[1]);
    o0.z = tanhf(acc[2]); o0.w = tanhf(acc[3]);
    o1.x = tanhf(acc[4]); o1.y = tanhf(acc[5]);
    o1.z = tanhf(acc[6]); o1.w = tanhf(acc[7]);
    float* op = out + (size_t)n * DF + f * 8;
    *(float4*)op       = o0;
    *(float4*)(op + 4) = o1;
}

// ---------------------------------------------------------------------------
extern "C" void kernel_launch(void* const* d_in, const int* in_sizes, int n_in,
                              void* d_out, int out_size, void* d_ws, size_t ws_size,
                              hipStream_t stream)
{
    const float* X    = (const float*)d_in[0];   // [N, 128]
    const float* W    = (const float*)d_in[1];   // [128, 128]
    const float* bias = (const float*)d_in[2];   // [128]
    const int*   arow = (const int*)  d_in[3];   // [E] sorted
    const int*   acol = (const int*)  d_in[4];   // [E]
    const float* aval = (const float*)d_in[5];   // [E]
    float* out = (float*)d_out;

    const int N = in_sizes[0] / DF;
    const int E = in_sizes[3];

    // ws layout: S [N*128 fp16] | rowptr [N+2] | pk [E int2]
    __half* S      = (__half*)d_ws;
    int*    rowptr = (int*)((char*)d_ws + (size_t)N * DF * sizeof(__half));
    int2*   pk     = (int2*)(rowptr + (N + 2));

    const int gemmBlocks = (N + 63) / 64;
    gemm_meta_kernel<<<gemmBlocks, 256, 0, stream>>>(X, W, bias, S,
                                                     arow, acol, aval,
                                                     rowptr, pk, N, E,
                                                     gemmBlocks * 256);

    agg_tanh_kernel<<<(N * 16 + 255) / 256, 256, 0, stream>>>(S, rowptr, pk, out, N);
}

// Round 3
// 123.566 us; speedup vs baseline: 1.0686x; 1.0074x over previous
//
#include <hip/hip_runtime.h>
#include <hip/hip_fp16.h>
#include <cmath>

#define DF 128            // feature dim
#define WPITCHH 136       // LDS W row pitch in halves (128 + 8 pad, 272 B)

typedef _Float16 f16x8 __attribute__((ext_vector_type(8)));
typedef _Float16 f16x4 __attribute__((ext_vector_type(4)));
typedef float    f32x4 __attribute__((ext_vector_type(4)));

// ---------------------------------------------------------------------------
// Kernel A: fused {edge-meta build + CSR rowptr} + {support GEMM via MFMA}.
// Meta work is grid-strided across the GEMM grid and issued FIRST so its
// loads/stores overlap the block's W-staging + X-load latency. W is converted
// fp32->fp16 on the fly while staging into LDS.
// GEMM: one 64-lane wave per 16-row m-strip, 4 waves/block, operand-swapped
// mfma(W,X) so the epilogue is 8 f16x4 stores per lane.
// (Proven neutral-vs-separate in R2 bisection; keeps launch count at 2.)
// ---------------------------------------------------------------------------
__global__ __launch_bounds__(256)
void gemm_meta_kernel(const float* __restrict__ X, const float* __restrict__ W,
                      const float* __restrict__ bias, __half* __restrict__ S,
                      const int* __restrict__ arow, const int* __restrict__ acol,
                      const float* __restrict__ aval,
                      int* __restrict__ rowptr, int2* __restrict__ pk,
                      int N, int E, int nthreads)
{
    __shared__ _Float16 Wl[DF * WPITCHH];          // 34 KB

    const int t   = threadIdx.x;
    const int tid = blockIdx.x * 256 + t;

    // ---- meta: packed edge {byte_offset, val_bits} + CSR rowptr ----
    for (int e = tid; e < E; e += nthreads) {
        pk[e] = make_int2(acol[e] << 8, __float_as_int(aval[e]));
        int r     = arow[e];
        int rprev = (e == 0) ? -1 : arow[e - 1];
        for (int n = rprev + 1; n <= r; ++n) rowptr[n] = e;
        if (e == E - 1) {
            for (int n = r + 1; n <= N; ++n) rowptr[n] = E;
        }
    }

    // ---- stage W into LDS, converting fp32 -> fp16 in flight ----
    #pragma unroll
    for (int l = 0; l < 8; ++l) {
        int flat = l * 256 + t;                    // 0..2047
        int r    = flat >> 4;                      // 0..127
        int c8   = (flat & 15) * 8;                // 0..120
        const float* wp = W + (size_t)r * DF + c8;
        float4 wa = *(const float4*)wp;
        float4 wb = *(const float4*)(wp + 4);
        f16x8 v;
        v[0] = (_Float16)wa.x; v[1] = (_Float16)wa.y;
        v[2] = (_Float16)wa.z; v[3] = (_Float16)wa.w;
        v[4] = (_Float16)wb.x; v[5] = (_Float16)wb.y;
        v[6] = (_Float16)wb.z; v[7] = (_Float16)wb.w;
        *(f16x8*)(Wl + r * WPITCHH + c8) = v;
    }
    __syncthreads();

    const int lane = t & 63;
    const int l15  = lane & 15;
    const int q    = lane >> 4;                    // 0..3
    const int m0   = (blockIdx.x * 4 + (t >> 6)) * 16;
    if (m0 >= N) return;

    f32x4 acc[8];
    #pragma unroll
    for (int nt = 0; nt < 8; ++nt) acc[nt] = (f32x4){0.f, 0.f, 0.f, 0.f};

    const int xrow = min(m0 + l15, N - 1);         // clamp (dup read) for tail
    #pragma unroll
    for (int kc = 0; kc < DF; kc += 32) {
        const float* xp = X + (size_t)xrow * DF + kc + q * 8;
        float4 xa = *(const float4*)xp;
        float4 xb = *(const float4*)(xp + 4);
        f16x8 A;
        A[0] = (_Float16)xa.x; A[1] = (_Float16)xa.y;
        A[2] = (_Float16)xa.z; A[3] = (_Float16)xa.w;
        A[4] = (_Float16)xb.x; A[5] = (_Float16)xb.y;
        A[6] = (_Float16)xb.z; A[7] = (_Float16)xb.w;
        #pragma unroll
        for (int nt = 0; nt < 8; ++nt) {
            f16x8 B = *(const f16x8*)(Wl + (nt * 16 + l15) * WPITCHH + kc + q * 8);
            // swapped: first operand = W rows (o), second = X rows (node)
            acc[nt] = __builtin_amdgcn_mfma_f32_16x16x32_f16(B, A, acc[nt], 0, 0, 0);
        }
    }

    const int mrow = m0 + l15;
    if (mrow < N) {
        _Float16* rowp = (_Float16*)S + (size_t)mrow * DF;
        #pragma unroll
        for (int nt = 0; nt < 8; ++nt) {
            float4 bv = *(const float4*)(bias + nt * 16 + q * 4);
            f16x4 hv;
            hv[0] = (_Float16)(acc[nt][0] + bv.x);
            hv[1] = (_Float16)(acc[nt][1] + bv.y);
            hv[2] = (_Float16)(acc[nt][2] + bv.z);
            hv[3] = (_Float16)(acc[nt][3] + bv.w);
            *(f16x4*)(rowp + nt * 16 + q * 4) = hv;
        }
    }
}

// ---------------------------------------------------------------------------
// exp-based tanh: 1 - 2/(e^{2x}+1). __expf -> v_mul + v_exp_f32; IEEE divide.
// Abs err ~1e-6 (<< fp16 quantization already present in S). Handles large
// |x| naturally: e^inf -> +1, e^0 -> -1. No NaN paths for finite input.
// ---------------------------------------------------------------------------
__device__ __forceinline__ float tanh_fast(float x)
{
    float e = __expf(2.0f * x);
    return 1.0f - 2.0f / (e + 1.0f);
}

// ---------------------------------------------------------------------------
// Kernel B: out[n][:] = tanh( sum_e val[e]*S_fp16[col[e]][:] ) per CSR row.
// ONE 16-LANE GROUP PER NODE (proven structure from R0; R1 showed more-waves/
// less-work regresses). Changes vs R0:
//  * 8-edge unroll: 8 pk loads + 8 gathers in flight per group, dependent
//    pk->gather chain rounds per node drop 3.5 -> 2.
//  * branchless tail: index min(e+k,end-1) (always in-bounds), val cndmask'd
//    to 0 -> all 8 loads issue unconditionally, no exec-mask ladder.
//  * tanh_fast epilogue (saves ~20 VALU/feature vs libm tanhf).
// ---------------------------------------------------------------------------
__global__ __launch_bounds__(256)
void agg_tanh_kernel(const __half* __restrict__ S, const int* __restrict__ rowptr,
                     const int2* __restrict__ pk, float* __restrict__ out, int Nn)
{
    const int n  = (blockIdx.x * 256 + threadIdx.x) >> 4;   // node = global group
    if (n >= Nn) return;
    const int f  = threadIdx.x & 15;                        // feature chunk
    const int fb = f * 16;                                  // byte offset in row

    const int start = rowptr[n];
    const int end   = rowptr[n + 1];
    const char* Sb  = (const char*)S;

    float acc[8];
    #pragma unroll
    for (int i = 0; i < 8; ++i) acc[i] = 0.f;

    const int last = end - 1;
    for (int e = start; e < end; e += 8) {
        int2 p0 = pk[min(e    , last)];
        int2 p1 = pk[min(e + 1, last)];
        int2 p2 = pk[min(e + 2, last)];
        int2 p3 = pk[min(e + 3, last)];
        int2 p4 = pk[min(e + 4, last)];
        int2 p5 = pk[min(e + 5, last)];
        int2 p6 = pk[min(e + 6, last)];
        int2 p7 = pk[min(e + 7, last)];
        f16x8 h0 = *(const f16x8*)(Sb + (size_t)(unsigned)p0.x + fb);
        f16x8 h1 = *(const f16x8*)(Sb + (size_t)(unsigned)p1.x + fb);
        f16x8 h2 = *(const f16x8*)(Sb + (size_t)(unsigned)p2.x + fb);
        f16x8 h3 = *(const f16x8*)(Sb + (size_t)(unsigned)p3.x + fb);
        f16x8 h4 = *(const f16x8*)(Sb + (size_t)(unsigned)p4.x + fb);
        f16x8 h5 = *(const f16x8*)(Sb + (size_t)(unsigned)p5.x + fb);
        f16x8 h6 = *(const f16x8*)(Sb + (size_t)(unsigned)p6.x + fb);
        f16x8 h7 = *(const f16x8*)(Sb + (size_t)(unsigned)p7.x + fb);
        const float v0 = __int_as_float(p0.y);
        const float v1 = (e + 1 < end) ? __int_as_float(p1.y) : 0.f;
        const float v2 = (e + 2 < end) ? __int_as_float(p2.y) : 0.f;
        const float v3 = (e + 3 < end) ? __int_as_float(p3.y) : 0.f;
        const float v4 = (e + 4 < end) ? __int_as_float(p4.y) : 0.f;
        const float v5 = (e + 5 < end) ? __int_as_float(p5.y) : 0.f;
        const float v6 = (e + 6 < end) ? __int_as_float(p6.y) : 0.f;
        const float v7 = (e + 7 < end) ? __int_as_float(p7.y) : 0.f;
        #pragma unroll
        for (int i = 0; i < 8; ++i) {
            acc[i] += (float)h0[i] * v0 + (float)h1[i] * v1
                    + (float)h2[i] * v2 + (float)h3[i] * v3
                    + (float)h4[i] * v4 + (float)h5[i] * v5
                    + (float)h6[i] * v6 + (float)h7[i] * v7;
        }
    }

    float4 o0, o1;
    o0.x = tanh_fast(acc[0]); o0.y = tanh_fast(acc[1]);
    o0.z = tanh_fast(acc[2]); o0.w = tanh_fast(acc[3]);
    o1.x = tanh_fast(acc[4]); o1.y = tanh_fast(acc[5]);
    o1.z = tanh_fast(acc[6]); o1.w = tanh_fast(acc[7]);
    float* op = out + (size_t)n * DF + f * 8;
    *(float4*)op       = o0;
    *(float4*)(op + 4) = o1;
}

// ---------------------------------------------------------------------------
extern "C" void kernel_launch(void* const* d_in, const int* in_sizes, int n_in,
                              void* d_out, int out_size, void* d_ws, size_t ws_size,
                              hipStream_t stream)
{
    const float* X    = (const float*)d_in[0];   // [N, 128]
    const float* W    = (const float*)d_in[1];   // [128, 128]
    const float* bias = (const float*)d_in[2];   // [128]
    const int*   arow = (const int*)  d_in[3];   // [E] sorted
    const int*   acol = (const int*)  d_in[4];   // [E]
    const float* aval = (const float*)d_in[5];   // [E]
    float* out = (float*)d_out;

    const int N = in_sizes[0] / DF;
    const int E = in_sizes[3];

    // ws layout: S [N*128 fp16] | rowptr [N+2] | pk [E int2]
    __half* S      = (__half*)d_ws;
    int*    rowptr = (int*)((char*)d_ws + (size_t)N * DF * sizeof(__half));
    int2*   pk     = (int2*)(rowptr + (N + 2));

    const int gemmBlocks = (N + 63) / 64;
    gemm_meta_kernel<<<gemmBlocks, 256, 0, stream>>>(X, W, bias, S,
                                                     arow, acol, aval,
                                                     rowptr, pk, N, E,
                                                     gemmBlocks * 256);

    agg_tanh_kernel<<<(N * 16 + 255) / 256, 256, 0, stream>>>(S, rowptr, pk, out, N);
}